// Round 4
// baseline (56.131 us; speedup 1.0000x reference)
//
#include <hip/hip_runtime.h>
#include <cstdint>

// I-BERT IntSoftmax, single pass, division-free, row-pipelined.
//
// Exactness (must match JAX/numpy f32 bit-for-bit):
//  - Global QuantAct max over exp_int is analytically ci*2^30 (attained at each
//    row argmax: q=0,r=0,z=ci; all others <= since r*(r+bi)<=0, 2^(30-q)<=2^30,
//    products exact) -> no device-wide reduction.
//  - Wave-uniform divisors: Markstein correction with y=RN(1/b) gives the
//    correctly-rounded IEEE quotient (3 ops vs ~14 for v_div expansion).
//  - floor(v/x0i): integer operands; 1-ulp-up reciprocal makes floorf exact.
//  - z in (0,2^24) integer, 2^(30-q) exact power of two -> floor/max no-ops.
//  - out_int: floor(eq*(factor*2^-25)) == floor(RN(eq*factor)/2^25) since
//    power-of-2 scaling commutes with RN (eq*factor < 2^32, no over/underflow).
//  - All integer intermediates (incl. row partial sums < 2^24 for this data
//    regime) exact in f32 -> summation order irrelevant (verified absmax 0).

typedef float floatx4 __attribute__((ext_vector_type(4)));

static __device__ __forceinline__ float wave_max(float v) {
#pragma unroll
    for (int m = 32; m >= 1; m >>= 1) v = fmaxf(v, __shfl_xor(v, m, 64));
    return v;
}
static __device__ __forceinline__ float wave_sum(float v) {
#pragma unroll
    for (int m = 32; m >= 1; m >>= 1) v += __shfl_xor(v, m, 64);
    return v;
}
static __device__ __forceinline__ float div_cr(float a, float b, float y) {
    float q0 = a * y;
    float r0 = fmaf(-b, q0, a);
    return fmaf(r0, y, q0);
}

#define ROWS_PER_WAVE 4

__global__ __launch_bounds__(256) void intsoftmax_ibert_kernel(
    const float* __restrict__ x, const float* __restrict__ sfp,
    float* __restrict__ out, long long n_total)
{
    const float sfv = sfp[0];

    const float x0i = floorf(-0.6931f / sfv);                          // x0_int < 0
    const float bi  = floorf((float)(0.96963238 / 0.35815147) / sfv);  // b_int
    const float ci  = floorf((float)(1.0 / 0.35815147) / (sfv * sfv)); // c_int
    const float x0a = -x0i;
    const float hi  = 30.0f * x0a;
    const float as  = (ci * 1073741824.0f) / 32767.0f;                 // act_scale

    const float ysf = (float)(1.0 / (double)sfv);
    const float yas = (float)(1.0 / (double)as);
    const float rpu = __uint_as_float(__float_as_uint((float)(1.0 / (double)x0a)) + 1);

    const int lane = threadIdx.x & 63;
    const int wv   = threadIdx.x >> 6;
    const long long row0 = ((long long)blockIdx.x * 4 + wv) * ROWS_PER_WAVE;

    // Prime the pipeline: row0's four 16B loads.
    floatx4 L0, L1, L2, L3;
    {
        const floatx4* p = (const floatx4*)(x + row0 * 1024);
        L0 = p[lane]; L1 = p[lane + 64]; L2 = p[lane + 128]; L3 = p[lane + 192];
    }

#pragma unroll
    for (int t = 0; t < ROWS_PER_WAVE; ++t) {
        const long long row = row0 + t;

        // Prefetch next row while we compute this one.
        floatx4 N0, N1, N2, N3;
        if (t < ROWS_PER_WAVE - 1) {
            const floatx4* p = (const floatx4*)(x + (row + 1) * 1024);
            N0 = p[lane]; N1 = p[lane + 64]; N2 = p[lane + 128]; N3 = p[lane + 192];
        }

        float xi[16];
#pragma unroll
        for (int j = 0; j < 4; ++j) {
            xi[0  + j] = truncf(div_cr(L0[j], sfv, ysf));
            xi[4  + j] = truncf(div_cr(L1[j], sfv, ysf));
            xi[8  + j] = truncf(div_cr(L2[j], sfv, ysf));
            xi[12 + j] = truncf(div_cr(L3[j], sfv, ysf));
        }

        float m = xi[0];
#pragma unroll
        for (int i = 1; i < 16; ++i) m = fmaxf(m, xi[i]);
        m = wave_max(m);

        float eq[16];
        float lsum = 0.0f;
#pragma unroll
        for (int i = 0; i < 16; ++i) {
            float vp = fminf(m - xi[i], hi);              // -v in [0, 30*x0a]
            float q  = floorf(vp * rpu);                  // exact floor(v/x0i)
            float r  = fmaf(x0a, q, -vp);                 // exact int in (-x0a, 0]
            float z  = fmaf(r, r + bi, ci);               // exact int < 2^24
            float p2 = __uint_as_float((uint32_t)(157 - (int)q) << 23); // 2^(30-q)
            float e  = z * p2;                            // exp_int, exact
            float t2 = rintf(div_cr(e, as, yas));         // round-half-even
            t2 = fminf(t2, 32767.0f);
            eq[i] = t2;
            lsum += t2;
        }
        float s = wave_sum(lsum);
        float factor  = floorf(4294967296.0f / s);        // once/row: real div
        float factor2 = factor * (1.0f / 33554432.0f);    // exact pow2 scale

        floatx4* orow = (floatx4*)(out + row * 1024);
#pragma unroll
        for (int k = 0; k < 4; ++k) {
            floatx4 o;
#pragma unroll
            for (int j = 0; j < 4; ++j)
                o[j] = floorf(eq[4 * k + j] * factor2) * 0.0078125f;
            __builtin_nontemporal_store(o, &orow[lane + 64 * k]);
        }

        if (t < ROWS_PER_WAVE - 1) { L0 = N0; L1 = N1; L2 = N2; L3 = N3; }
    }

    if (blockIdx.x == 0 && threadIdx.x == 0) out[n_total] = 0.0078125f;
}

extern "C" void kernel_launch(void* const* d_in, const int* in_sizes, int n_in,
                              void* d_out, int out_size, void* d_ws, size_t ws_size,
                              hipStream_t stream) {
    const float* x  = (const float*)d_in[0];
    const float* sf = (const float*)d_in[1];
    float* out = (float*)d_out;

    const long long n_total = (long long)out_size - 1;   // 4*12*1024*1024
    const int rows = (int)(n_total / 1024);              // 49152
    const int grid = rows / (4 * ROWS_PER_WAVE);         // 3072 blocks

    intsoftmax_ibert_kernel<<<grid, 256, 0, stream>>>(x, sf, out, n_total);
}

// Round 5
// 55.220 us; speedup vs baseline: 1.0165x; 1.0165x over previous
//
#include <hip/hip_runtime.h>
#include <cstdint>

// I-BERT IntSoftmax, single pass, division-free, 2-row pipelined.
//
// Exactness (must match JAX/numpy f32 bit-for-bit):
//  - Global QuantAct max over exp_int is analytically ci*2^30 (attained at each
//    row argmax: q=0,r=0,z=ci; all others <= since r*(r+bi)<=0, 2^(30-q)<=2^30,
//    products exact) -> no device-wide reduction.
//  - Wave-uniform divisors: Markstein correction with y=RN(1/b) gives the
//    correctly-rounded IEEE quotient.
//  - floor(v/x0i): integer operands; 1-ulp-up reciprocal makes floorf exact.
//  - z in (0,2^24) integer, 2^(30-q) exact power of two -> floor/max no-ops.
//  - clip at 32767: max quotient is within ~0.002 of 32767 -> rint == 32767,
//    clip is a no-op, dropped.
//  - out_int: floor(eq*(factor*2^-25)) == floor((eq*factor)/2^25): pow-2
//    scaling commutes with RN, eq*factor < 2^32.
//  - Integer intermediates (partial sums < 2^24) exact in f32 (absmax 0
//    verified in R1/R3/R4).

typedef float floatx4 __attribute__((ext_vector_type(4)));

static __device__ __forceinline__ float wave_max(float v) {
#pragma unroll
    for (int m = 32; m >= 1; m >>= 1) v = fmaxf(v, __shfl_xor(v, m, 64));
    return v;
}
static __device__ __forceinline__ float wave_sum(float v) {
#pragma unroll
    for (int m = 32; m >= 1; m >>= 1) v += __shfl_xor(v, m, 64);
    return v;
}
static __device__ __forceinline__ float div_cr(float a, float b, float y) {
    float q0 = a * y;
    float r0 = fmaf(-b, q0, a);
    return fmaf(r0, y, q0);
}

#define ROWS_PER_WAVE 2   // 49152/(4*2) = 6144 blocks = 24576 waves = 3 full batches

__global__ __launch_bounds__(256) void intsoftmax_ibert_kernel(
    const float* __restrict__ x, const float* __restrict__ sfp,
    float* __restrict__ out, long long n_total)
{
    const float sfv = sfp[0];

    const float x0i = floorf(-0.6931f / sfv);                          // x0_int < 0
    const float bi  = floorf((float)(0.96963238 / 0.35815147) / sfv);  // b_int
    const float ci  = floorf((float)(1.0 / 0.35815147) / (sfv * sfv)); // c_int
    const float x0a = -x0i;
    const float hi  = 30.0f * x0a;
    const float as  = (ci * 1073741824.0f) / 32767.0f;                 // act_scale

    const float ysf = (float)(1.0 / (double)sfv);
    const float yas = (float)(1.0 / (double)as);
    const float rpu = __uint_as_float(__float_as_uint((float)(1.0 / (double)x0a)) + 1);

    const int lane = threadIdx.x & 63;
    const int wv   = threadIdx.x >> 6;
    const long long row0 = ((long long)blockIdx.x * 4 + wv) * ROWS_PER_WAVE;

    // Prime: row0's four 16B loads.
    floatx4 L0, L1, L2, L3;
    {
        const floatx4* p = (const floatx4*)(x + row0 * 1024);
        L0 = p[lane]; L1 = p[lane + 64]; L2 = p[lane + 128]; L3 = p[lane + 192];
    }

#pragma unroll
    for (int t = 0; t < ROWS_PER_WAVE; ++t) {
        const long long row = row0 + t;

        // Prefetch next row while computing this one.
        floatx4 N0, N1, N2, N3;
        if (t < ROWS_PER_WAVE - 1) {
            const floatx4* p = (const floatx4*)(x + (row + 1) * 1024);
            N0 = p[lane]; N1 = p[lane + 64]; N2 = p[lane + 128]; N3 = p[lane + 192];
        }

        float xi[16];
#pragma unroll
        for (int j = 0; j < 4; ++j) {
            xi[0  + j] = truncf(div_cr(L0[j], sfv, ysf));
            xi[4  + j] = truncf(div_cr(L1[j], sfv, ysf));
            xi[8  + j] = truncf(div_cr(L2[j], sfv, ysf));
            xi[12 + j] = truncf(div_cr(L3[j], sfv, ysf));
        }

        float m = xi[0];
#pragma unroll
        for (int i = 1; i < 16; ++i) m = fmaxf(m, xi[i]);
        m = wave_max(m);

        // exp_int + QuantAct requant; recycle xi[] as eq[] to cap VGPRs.
        float lsum = 0.0f;
#pragma unroll
        for (int i = 0; i < 16; ++i) {
            float vp = fminf(m - xi[i], hi);              // -v in [0, 30*x0a]
            float q  = floorf(vp * rpu);                  // exact floor(v/x0i)
            float r  = fmaf(x0a, q, -vp);                 // exact int in (-x0a, 0]
            float z  = fmaf(r, r + bi, ci);               // exact int < 2^24
            float p2 = __uint_as_float((uint32_t)(157 - (int)q) << 23); // 2^(30-q)
            float t2 = rintf(div_cr(z * p2, as, yas));    // round-half-even
            xi[i] = t2;
            lsum += t2;
        }
        float s = wave_sum(lsum);
        float factor  = floorf(4294967296.0f / s);        // once/row: real div
        float factor2 = factor * (1.0f / 33554432.0f);    // exact pow2 fold

        floatx4* orow = (floatx4*)(out + row * 1024);
#pragma unroll
        for (int k = 0; k < 4; ++k) {
            floatx4 o;
#pragma unroll
            for (int j = 0; j < 4; ++j)
                o[j] = floorf(xi[4 * k + j] * factor2) * 0.0078125f;
            __builtin_nontemporal_store(o, &orow[lane + 64 * k]);
        }

        if (t < ROWS_PER_WAVE - 1) { L0 = N0; L1 = N1; L2 = N2; L3 = N3; }
    }

    if (blockIdx.x == 0 && threadIdx.x == 0) out[n_total] = 0.0078125f;
}

extern "C" void kernel_launch(void* const* d_in, const int* in_sizes, int n_in,
                              void* d_out, int out_size, void* d_ws, size_t ws_size,
                              hipStream_t stream) {
    const float* x  = (const float*)d_in[0];
    const float* sf = (const float*)d_in[1];
    float* out = (float*)d_out;

    const long long n_total = (long long)out_size - 1;   // 4*12*1024*1024
    const int rows = (int)(n_total / 1024);              // 49152
    const int grid = rows / (4 * ROWS_PER_WAVE);         // 6144 blocks

    intsoftmax_ibert_kernel<<<grid, 256, 0, stream>>>(x, sf, out, n_total);
}